// Round 1
// baseline (11234.421 us; speedup 1.0000x reference)
//
#include <hip/hip_runtime.h>

typedef unsigned short u16;
typedef unsigned int   u32;
typedef __attribute__((ext_vector_type(8))) __bf16 bf16x8;
typedef __attribute__((ext_vector_type(4))) float  f32x4;

#define NWG    128
#define TSTEPS 512

// ---------------- helpers ----------------
__device__ __forceinline__ u16 f2bf(float f) {
  union { float f; u32 u; } v; v.f = f;
  return (u16)((v.u + 0x7FFFu + ((v.u >> 16) & 1u)) >> 16);  // RNE
}
__device__ __forceinline__ float sigf(float x)     { return 1.f / (1.f + __expf(-x)); }
__device__ __forceinline__ float tanhfast(float x) { return 2.f / (1.f + __expf(-2.f * x)) - 1.f; }

// fp32 -> bf16 bulk convert (also used for h0)
__global__ void convert_x_kernel(const float* __restrict__ x, u16* __restrict__ xb, long n) {
  long i = (long)(blockIdx.x * blockDim.x + threadIdx.x) * 4;
  long stride = (long)gridDim.x * blockDim.x * 4;
  for (; i < n; i += stride) {
    float4 v = *reinterpret_cast<const float4*>(x + i);
    ushort4 o; o.x = f2bf(v.x); o.y = f2bf(v.y); o.z = f2bf(v.z); o.w = f2bf(v.w);
    *reinterpret_cast<ushort4*>(xb + i) = o;
  }
}

// Gather W into exact per-(wg,wave,ks,tile,lane) MFMA B-fragment order, bf16.
// Fragment assumption (consistent for A and B, so k-permutation cancels):
//   B[k][col]: col = lane&15, k = ks*32 + (lane>>4)*8 + b
// WG n owns cols c=0..31 -> gate g = c>>3, j = n*8 + (c&7). Wave w owns k in [512w, 512w+512).
__global__ void arrange_w_kernel(const float* __restrict__ Wf, const float* __restrict__ Wi,
                                 const float* __restrict__ Wc, const float* __restrict__ Wo,
                                 u16* __restrict__ wfrag) {
  __shared__ float lds[4][512][8];
  const int n = blockIdx.x >> 2;      // 0..127
  const int w = blockIdx.x & 3;       // 0..3
  const int tid = threadIdx.x;
  #pragma unroll
  for (int g = 0; g < 4; ++g) {
    const float* W = (g == 0) ? Wf : (g == 1) ? Wi : (g == 2) ? Wc : Wo;
    for (int it = 0; it < 16; ++it) {
      int e = it * 256 + tid;
      int kk = e >> 3, jj = e & 7;
      lds[g][kk][jj] = W[(size_t)(w * 512 + kk) * 1024 + n * 8 + jj];
    }
  }
  __syncthreads();
  u16* outp = wfrag + ((size_t)blockIdx.x << 14);   // 16384 elems per (n,w)
  for (int it = 0; it < 64; ++it) {
    int e = it * 256 + tid;
    int b = e & 7, lane = (e >> 3) & 63, tile = (e >> 9) & 1, ks = e >> 10;
    int kk = ks * 32 + ((lane >> 4) << 3) + b;
    int c  = tile * 16 + (lane & 15);
    int g  = c >> 3, jj = c & 7;
    outp[e] = f2bf(lds[g][kk][jj]);
  }
}

// device-scope grid barrier (counter + generation)
__device__ __forceinline__ void grid_barrier(u32* bar, u32 nwg) {
  __syncthreads();
  if (threadIdx.x == 0) {
    __threadfence();  // agent-scope release of all prior writes (h slices)
    u32 g = __hip_atomic_load(bar + 1, __ATOMIC_RELAXED, __HIP_MEMORY_SCOPE_AGENT);
    u32 a = __hip_atomic_fetch_add(bar, 1u, __ATOMIC_ACQ_REL, __HIP_MEMORY_SCOPE_AGENT);
    if (a == nwg - 1u) {
      __hip_atomic_store(bar, 0u, __ATOMIC_RELAXED, __HIP_MEMORY_SCOPE_AGENT);
      __hip_atomic_fetch_add(bar + 1, 1u, __ATOMIC_RELEASE, __HIP_MEMORY_SCOPE_AGENT);
    } else {
      while (__hip_atomic_load(bar + 1, __ATOMIC_ACQUIRE, __HIP_MEMORY_SCOPE_AGENT) == g)
        __builtin_amdgcn_s_sleep(2);
    }
  }
  __syncthreads();
}

// Persistent LSTM: 128 WGs x 256 thr. WG n owns j in [8n, 8n+8) (32 gate-cols).
// Wave w holds B-frags for its K-slice [512w,512w+512) in 128 VGPRs for all 512 steps.
// waves 0,1: A from h (recurrent); waves 2,3: A from x. K-split partials reduced in LDS.
__launch_bounds__(256, 1)
__global__ void lstm_main_kernel(
    const u16* __restrict__ xbf, const u16* __restrict__ wfrag,
    const float* __restrict__ c0,
    const float* __restrict__ bF, const float* __restrict__ bI,
    const float* __restrict__ bC, const float* __restrict__ bO,
    u16* __restrict__ hb, float* __restrict__ out, u32* bar)
{
  const int n    = blockIdx.x;
  const int tid  = threadIdx.x;
  const int w    = tid >> 6;
  const int lane = tid & 63;
  const int lr   = lane & 15;
  const int lk   = (lane >> 4) << 3;

  __shared__ float part[4][64][33];   // K-split partials, padded

  // persistent B fragments (W) — loaded once, live in registers across all steps
  bf16x8 bq[16][2];
  {
    const u16* wp = wfrag + ((size_t)(n * 4 + w) << 14) + lane * 8;
    #pragma unroll
    for (int ks = 0; ks < 16; ++ks) {
      bq[ks][0] = *reinterpret_cast<const bf16x8*>(wp + ks * 1024);
      bq[ks][1] = *reinterpret_cast<const bf16x8*>(wp + ks * 1024 + 512);
    }
  }

  // elementwise ownership: thread -> (row, jj0=even jj), c-state in fp32 registers
  const int erow = tid >> 2;
  const int ejj  = (tid & 3) << 1;
  const int j0   = n * 8 + ejj;
  float cR0 = c0[erow * 1024 + j0];
  float cR1 = c0[erow * 1024 + j0 + 1];
  const float bf0 = bF[j0], bf1 = bF[j0 + 1];
  const float bi0 = bI[j0], bi1 = bI[j0 + 1];
  const float bc0 = bC[j0], bc1 = bC[j0 + 1];
  const float bo0 = bO[j0], bo1 = bO[j0 + 1];

  #pragma unroll 1
  for (int t = 0; t < TSTEPS; ++t) {
    const u16* asrc = (w < 2) ? (hb + (t & 1) * 65536 + w * 512)
                              : (xbf + (size_t)t * 65536 + (w - 2) * 512);

    f32x4 acc[4][2];
    #pragma unroll
    for (int m = 0; m < 4; ++m) {
      acc[m][0] = (f32x4){0.f, 0.f, 0.f, 0.f};
      acc[m][1] = (f32x4){0.f, 0.f, 0.f, 0.f};
    }

    #pragma unroll
    for (int ks = 0; ks < 16; ++ks) {
      #pragma unroll
      for (int m = 0; m < 4; ++m) {
        bf16x8 av = *reinterpret_cast<const bf16x8*>(asrc + (m * 16 + lr) * 1024 + ks * 32 + lk);
        acc[m][0] = __builtin_amdgcn_mfma_f32_16x16x32_bf16(av, bq[ks][0], acc[m][0], 0, 0, 0);
        acc[m][1] = __builtin_amdgcn_mfma_f32_16x16x32_bf16(av, bq[ks][1], acc[m][1], 0, 0, 0);
      }
    }

    // write K-split partials: D row = m*16 + (lane>>4)*4 + r, col = nt*16 + lr
    #pragma unroll
    for (int m = 0; m < 4; ++m)
      #pragma unroll
      for (int nt = 0; nt < 2; ++nt)
        #pragma unroll
        for (int r = 0; r < 4; ++r)
          part[w][m * 16 + ((lane >> 4) << 2) + r][nt * 16 + lr] = acc[m][nt][r];

    __syncthreads();

    // reduce 4 partials + bias + gates + state update (2 elems per thread)
    float a8[8];
    #pragma unroll
    for (int q = 0; q < 2; ++q) {
      int jj = ejj + q;
      #pragma unroll
      for (int g = 0; g < 4; ++g)
        a8[q * 4 + g] = part[0][erow][g * 8 + jj] + part[1][erow][g * 8 + jj]
                      + part[2][erow][g * 8 + jj] + part[3][erow][g * 8 + jj];
    }
    float fA = sigf(a8[0] + bf0), iA = sigf(a8[1] + bi0);
    float gA = tanhfast(a8[2] + bc0), oA = sigf(a8[3] + bo0);
    float cn0 = fA * cR0 + iA * gA;
    float hn0 = oA * tanhfast(cn0);
    cR0 = cn0;
    float fB = sigf(a8[4] + bf1), iB = sigf(a8[5] + bi1);
    float gB = tanhfast(a8[6] + bc1), oB = sigf(a8[7] + bo1);
    float cn1 = fB * cR1 + iB * gB;
    float hn1 = oB * tanhfast(cn1);
    cR1 = cn1;

    u16* hdst = hb + ((t + 1) & 1) * 65536;
    hdst[erow * 1024 + j0]     = f2bf(hn0);
    hdst[erow * 1024 + j0 + 1] = f2bf(hn1);
    size_t ob = (size_t)t * 65536 + erow * 1024 + j0;
    out[ob]     = hn0;
    out[ob + 1] = hn1;
    if (t == TSTEPS - 1) {
      out[33554432 + erow * 1024 + j0]     = hn0;   // h_last
      out[33554432 + erow * 1024 + j0 + 1] = hn1;
      out[33619968 + erow * 1024 + j0]     = cn0;   // c_last
      out[33619968 + erow * 1024 + j0 + 1] = cn1;
    }

    grid_barrier(bar, NWG);  // h_t visible to all before step t+1
  }
}

extern "C" void kernel_launch(void* const* d_in, const int* in_sizes, int n_in,
                              void* d_out, int out_size, void* d_ws, size_t ws_size,
                              hipStream_t stream) {
  const float* x  = (const float*)d_in[0];
  const float* h0 = (const float*)d_in[1];
  const float* c0 = (const float*)d_in[2];
  const float* Wf = (const float*)d_in[3];
  const float* bf = (const float*)d_in[4];
  const float* Wi = (const float*)d_in[5];
  const float* bi = (const float*)d_in[6];
  const float* Wc = (const float*)d_in[7];
  const float* bc = (const float*)d_in[8];
  const float* Wo = (const float*)d_in[9];
  const float* bo = (const float*)d_in[10];

  // workspace layout: wfrag 16MB | xbf 64MB | hb 256KB | bar 64B  (~80.3 MB)
  if (ws_size < ((80u << 20) + (1u << 18) + 1024)) return;  // fail visibly if ws too small
  char* ws   = (char*)d_ws;
  u16* wfrag = (u16*)ws;
  u16* xbf   = (u16*)(ws + (16u << 20));
  u16* hb    = (u16*)(ws + (80u << 20));
  u32* bar   = (u32*)(ws + (80u << 20) + (1u << 18));
  float* outp = (float*)d_out;

  hipMemsetAsync(bar, 0, 64, stream);
  convert_x_kernel<<<2048, 256, 0, stream>>>(x, xbf, (long)512 * 64 * 1024);
  convert_x_kernel<<<64, 256, 0, stream>>>(h0, hb, 65536);
  arrange_w_kernel<<<512, 256, 0, stream>>>(Wf, Wi, Wc, Wo, wfrag);

  void* args[] = {(void*)&xbf, (void*)&wfrag, (void*)&c0, (void*)&bf, (void*)&bi,
                  (void*)&bc, (void*)&bo, (void*)&hb, (void*)&outp, (void*)&bar};
  hipLaunchCooperativeKernel((const void*)lstm_main_kernel, dim3(NWG), dim3(256),
                             args, 0, stream);
}

// Round 4
// 8639.261 us; speedup vs baseline: 1.3004x; 1.3004x over previous
//
#include <hip/hip_runtime.h>

typedef unsigned short u16;
typedef unsigned int   u32;
typedef __attribute__((ext_vector_type(8))) __bf16 bf16x8;
typedef __attribute__((ext_vector_type(4))) float  f32x4;

#define NWG    128
#define TSTEPS 512

// ---------------- helpers ----------------
__device__ __forceinline__ u16 f2bf(float f) {
  union { float f; u32 u; } v; v.f = f;
  return (u16)((v.u + 0x7FFFu + ((v.u >> 16) & 1u)) >> 16);  // RNE
}
__device__ __forceinline__ float sigf(float x)     { return 1.f / (1.f + __expf(-x)); }
__device__ __forceinline__ float tanhfast(float x) { return 2.f / (1.f + __expf(-2.f * x)) - 1.f; }

// fp32 -> bf16 bulk convert (also used for h0)
__global__ void convert_x_kernel(const float* __restrict__ x, u16* __restrict__ xb, long n) {
  long i = (long)(blockIdx.x * blockDim.x + threadIdx.x) * 4;
  long stride = (long)gridDim.x * blockDim.x * 4;
  for (; i < n; i += stride) {
    float4 v = *reinterpret_cast<const float4*>(x + i);
    ushort4 o; o.x = f2bf(v.x); o.y = f2bf(v.y); o.z = f2bf(v.z); o.w = f2bf(v.w);
    *reinterpret_cast<ushort4*>(xb + i) = o;
  }
}

// Gather W into exact per-(wg,wave,ks,tile,lane) MFMA B-fragment order, bf16.
// (identical to the R1 PASSING version)
// B[k][col]: col = lane&15, k = ks*32 + (lane>>4)*8 + b
// WG n owns cols c=0..31 -> gate g = c>>3, j = n*8 + (c&7). Wave w owns k in [512w, 512w+512).
__global__ void arrange_w_kernel(const float* __restrict__ Wf, const float* __restrict__ Wi,
                                 const float* __restrict__ Wc, const float* __restrict__ Wo,
                                 u16* __restrict__ wfrag) {
  __shared__ float lds[4][512][8];
  const int n = blockIdx.x >> 2;      // 0..127
  const int w = blockIdx.x & 3;       // 0..3
  const int tid = threadIdx.x;
  #pragma unroll
  for (int g = 0; g < 4; ++g) {
    const float* W = (g == 0) ? Wf : (g == 1) ? Wi : (g == 2) ? Wc : Wo;
    for (int it = 0; it < 16; ++it) {
      int e = it * 256 + tid;
      int kk = e >> 3, jj = e & 7;
      lds[g][kk][jj] = W[(size_t)(w * 512 + kk) * 1024 + n * 8 + jj];
    }
  }
  __syncthreads();
  u16* outp = wfrag + ((size_t)blockIdx.x << 14);   // 16384 elems per (n,w)
  for (int it = 0; it < 64; ++it) {
    int e = it * 256 + tid;
    int b = e & 7, lane = (e >> 3) & 63, tile = (e >> 9) & 1, ks = e >> 10;
    int kk = ks * 32 + ((lane >> 4) << 3) + b;
    int c  = tile * 16 + (lane & 15);
    int g  = c >> 3, jj = c & 7;
    outp[e] = f2bf(lds[g][kk][jj]);
  }
}

// Persistent LSTM: 128 WGs x 256 thr. WG n owns j in [8n, 8n+8) (32 gate-cols).
// Wave w holds B-frags for its K-slice [512w,512w+512) in registers (all steps).
// waves 0,1: A from h (recurrent); waves 2,3: A from x (no spin — overlaps wait).
// Sync protocol (R1-proven coherence chain, storm removed):
//   producer: __syncthreads (drains all waves' h stores to L2) ->
//             tid0 RELEASE flag store (one buffer_wbl2/WG/step, flushes L2 -> MALL)
//   consumer: RELAXED polls (sc1 read-through, no cache maintenance) ->
//             ONE ACQUIRE load (invalidate stale L1/L2) -> plain h loads
__launch_bounds__(256, 1)
__global__ void lstm_main_kernel(
    const u16* __restrict__ xbf, const u16* __restrict__ wfrag,
    const float* __restrict__ c0,
    const float* __restrict__ bF, const float* __restrict__ bI,
    const float* __restrict__ bC, const float* __restrict__ bO,
    u16* __restrict__ hb, float* __restrict__ out, u32* flags)
{
  const int n    = blockIdx.x;
  const int tid  = threadIdx.x;
  const int w    = tid >> 6;
  const int lane = tid & 63;
  const int lr   = lane & 15;
  const int lk   = (lane >> 4) << 3;

  __shared__ float part[4][64][33];   // K-split partials, padded

  // persistent B fragments (W) — loaded once, live in registers across all steps
  bf16x8 bq[16][2];
  {
    const u16* wp = wfrag + ((size_t)(n * 4 + w) << 14) + lane * 8;
    #pragma unroll
    for (int ks = 0; ks < 16; ++ks) {
      bq[ks][0] = *reinterpret_cast<const bf16x8*>(wp + ks * 1024);
      bq[ks][1] = *reinterpret_cast<const bf16x8*>(wp + ks * 1024 + 512);
    }
  }

  // elementwise ownership: thread -> (row, jj0=even jj), c-state in fp32 registers
  const int erow = tid >> 2;
  const int ejj  = (tid & 3) << 1;
  const int j0   = n * 8 + ejj;
  float cR0 = c0[erow * 1024 + j0];
  float cR1 = c0[erow * 1024 + j0 + 1];
  const float bf0 = bF[j0], bf1 = bF[j0 + 1];
  const float bi0 = bI[j0], bi1 = bI[j0 + 1];
  const float bc0 = bC[j0], bc1 = bC[j0 + 1];
  const float bo0 = bO[j0], bo1 = bO[j0 + 1];

  #pragma unroll 1
  for (int t = 0; t < TSTEPS; ++t) {
    // ---- recurrent waves wait for all WGs' step-(t-1) h; x waves proceed ----
    if (w < 2 && t > 0) {
      const u32 tv = (u32)t;
      while (true) {
        u32 f0 = __hip_atomic_load(flags + lane,      __ATOMIC_RELAXED, __HIP_MEMORY_SCOPE_AGENT);
        u32 f1 = __hip_atomic_load(flags + 64 + lane, __ATOMIC_RELAXED, __HIP_MEMORY_SCOPE_AGENT);
        if (__all((f0 >= tv) && (f1 >= tv))) break;
        __builtin_amdgcn_s_sleep(1);
      }
      // one acquire load: orders subsequent h loads + invalidates stale cache
      u32 d = __hip_atomic_load(flags + n, __ATOMIC_ACQUIRE, __HIP_MEMORY_SCOPE_AGENT);
      asm volatile("" :: "v"(d));   // keep the acquire load live
    }

    const u16* asrc = (w < 2) ? (hb + (t & 1) * 65536 + w * 512)
                              : (xbf + (size_t)t * 65536 + (w - 2) * 512);

    f32x4 acc[4][2];
    #pragma unroll
    for (int m = 0; m < 4; ++m) {
      acc[m][0] = (f32x4){0.f, 0.f, 0.f, 0.f};
      acc[m][1] = (f32x4){0.f, 0.f, 0.f, 0.f};
    }

    #pragma unroll
    for (int ks = 0; ks < 16; ++ks) {
      #pragma unroll
      for (int m = 0; m < 4; ++m) {
        bf16x8 av = *reinterpret_cast<const bf16x8*>(asrc + (m * 16 + lr) * 1024 + ks * 32 + lk);
        acc[m][0] = __builtin_amdgcn_mfma_f32_16x16x32_bf16(av, bq[ks][0], acc[m][0], 0, 0, 0);
        acc[m][1] = __builtin_amdgcn_mfma_f32_16x16x32_bf16(av, bq[ks][1], acc[m][1], 0, 0, 0);
      }
    }

    // write K-split partials: D row = m*16 + (lane>>4)*4 + r, col = nt*16 + lr
    #pragma unroll
    for (int m = 0; m < 4; ++m)
      #pragma unroll
      for (int nt = 0; nt < 2; ++nt)
        #pragma unroll
        for (int r = 0; r < 4; ++r)
          part[w][m * 16 + ((lane >> 4) << 2) + r][nt * 16 + lr] = acc[m][nt][r];

    __syncthreads();

    // reduce 4 partials + bias + gates + state update (2 elems per thread)
    float a8[8];
    #pragma unroll
    for (int q = 0; q < 2; ++q) {
      int jj = ejj + q;
      #pragma unroll
      for (int g = 0; g < 4; ++g)
        a8[q * 4 + g] = part[0][erow][g * 8 + jj] + part[1][erow][g * 8 + jj]
                      + part[2][erow][g * 8 + jj] + part[3][erow][g * 8 + jj];
    }
    float fA = sigf(a8[0] + bf0), iA = sigf(a8[1] + bi0);
    float gA = tanhfast(a8[2] + bc0), oA = sigf(a8[3] + bo0);
    float cn0 = fA * cR0 + iA * gA;
    float hn0 = oA * tanhfast(cn0);
    cR0 = cn0;
    float fB = sigf(a8[4] + bf1), iB = sigf(a8[5] + bi1);
    float gB = tanhfast(a8[6] + bc1), oB = sigf(a8[7] + bo1);
    float cn1 = fB * cR1 + iB * gB;
    float hn1 = oB * tanhfast(cn1);
    cR1 = cn1;

    // plain stores (R1-identical): h double-buffer + fp32 outputs
    u16* hdst = hb + ((t + 1) & 1) * 65536;
    hdst[erow * 1024 + j0]     = f2bf(hn0);
    hdst[erow * 1024 + j0 + 1] = f2bf(hn1);
    size_t ob = (size_t)t * 65536 + erow * 1024 + j0;
    out[ob]     = hn0;
    out[ob + 1] = hn1;
    if (t == TSTEPS - 1) {
      out[33554432 + erow * 1024 + j0]     = hn0;   // h_last
      out[33554432 + erow * 1024 + j0 + 1] = hn1;
      out[33619968 + erow * 1024 + j0]     = cn0;   // c_last
      out[33619968 + erow * 1024 + j0 + 1] = cn1;
    }

    // publish: barrier drains every wave's stores into L2, then tid0's RELEASE
    // store flushes L2 (one wbl2/WG/step) and makes the flag visible.
    __syncthreads();
    if (t < TSTEPS - 1 && tid == 0)
      __hip_atomic_store(flags + n, (u32)(t + 1), __ATOMIC_RELEASE, __HIP_MEMORY_SCOPE_AGENT);
  }
}

extern "C" void kernel_launch(void* const* d_in, const int* in_sizes, int n_in,
                              void* d_out, int out_size, void* d_ws, size_t ws_size,
                              hipStream_t stream) {
  const float* x  = (const float*)d_in[0];
  const float* h0 = (const float*)d_in[1];
  const float* c0 = (const float*)d_in[2];
  const float* Wf = (const float*)d_in[3];
  const float* bf = (const float*)d_in[4];
  const float* Wi = (const float*)d_in[5];
  const float* bi = (const float*)d_in[6];
  const float* Wc = (const float*)d_in[7];
  const float* bc = (const float*)d_in[8];
  const float* Wo = (const float*)d_in[9];
  const float* bo = (const float*)d_in[10];

  // workspace layout: wfrag 16MB | xbf 64MB | hb 256KB | flags 512B
  if (ws_size < ((80u << 20) + (1u << 18) + 1024)) return;
  char* ws   = (char*)d_ws;
  u16* wfrag = (u16*)ws;
  u16* xbf   = (u16*)(ws + (16u << 20));
  u16* hb    = (u16*)(ws + (80u << 20));
  u32* flags = (u32*)(ws + (80u << 20) + (1u << 18));
  float* outp = (float*)d_out;

  hipMemsetAsync(flags, 0, 512, stream);
  convert_x_kernel<<<2048, 256, 0, stream>>>(x, xbf, (long)512 * 64 * 1024);
  convert_x_kernel<<<64, 256, 0, stream>>>(h0, hb, 65536);
  arrange_w_kernel<<<512, 256, 0, stream>>>(Wf, Wi, Wc, Wo, wfrag);

  void* args[] = {(void*)&xbf, (void*)&wfrag, (void*)&c0, (void*)&bf, (void*)&bi,
                  (void*)&bc, (void*)&bo, (void*)&hb, (void*)&outp, (void*)&flags};
  hipError_t e = hipLaunchCooperativeKernel((const void*)lstm_main_kernel, dim3(NWG),
                                            dim3(256), args, 0, stream);
  if (e != hipSuccess) {
    // 128 WGs at 1 WG/CU on 256 CUs are trivially co-resident; plain launch is
    // a safe fallback so a silent cooperative-launch failure can't stub the run.
    lstm_main_kernel<<<dim3(NWG), dim3(256), 0, stream>>>(xbf, wfrag, c0, bf, bi,
                                                          bc, bo, hb, outp, flags);
  }
}

// Round 6
// 7446.129 us; speedup vs baseline: 1.5088x; 1.1602x over previous
//
#include <hip/hip_runtime.h>

typedef unsigned short u16;
typedef unsigned int   u32;
typedef unsigned long long u64;
typedef __attribute__((ext_vector_type(8))) __bf16 bf16x8;
typedef __attribute__((ext_vector_type(4))) float  f32x4;

#define NWG    128
#define TSTEPS 512

// ---------------- helpers ----------------
__device__ __forceinline__ u16 f2bf(float f) {
  union { float f; u32 u; } v; v.f = f;
  return (u16)((v.u + 0x7FFFu + ((v.u >> 16) & 1u)) >> 16);  // RNE
}
__device__ __forceinline__ float sigf(float x)     { return 1.f / (1.f + __expf(-x)); }
__device__ __forceinline__ float tanhfast(float x) { return 2.f / (1.f + __expf(-2.f * x)) - 1.f; }

// fp32 -> bf16 bulk convert (also used for h0)
__global__ void convert_x_kernel(const float* __restrict__ x, u16* __restrict__ xb, long n) {
  long i = (long)(blockIdx.x * blockDim.x + threadIdx.x) * 4;
  long stride = (long)gridDim.x * blockDim.x * 4;
  for (; i < n; i += stride) {
    float4 v = *reinterpret_cast<const float4*>(x + i);
    ushort4 o; o.x = f2bf(v.x); o.y = f2bf(v.y); o.z = f2bf(v.z); o.w = f2bf(v.w);
    *reinterpret_cast<ushort4*>(xb + i) = o;
  }
}

// Gather W into exact per-(wg,wave,ks,tile,lane) MFMA B-fragment order, bf16.
// (identical to the R1/R4 PASSING version)
// B[k][col]: col = lane&15, k = ks*32 + (lane>>4)*8 + b
// WG n owns cols c=0..31 -> gate g = c>>3, j = n*8 + (c&7). Wave w owns k in [512w, 512w+512).
__global__ void arrange_w_kernel(const float* __restrict__ Wf, const float* __restrict__ Wi,
                                 const float* __restrict__ Wc, const float* __restrict__ Wo,
                                 u16* __restrict__ wfrag) {
  __shared__ float lds[4][512][8];
  const int n = blockIdx.x >> 2;      // 0..127
  const int w = blockIdx.x & 3;       // 0..3
  const int tid = threadIdx.x;
  #pragma unroll
  for (int g = 0; g < 4; ++g) {
    const float* W = (g == 0) ? Wf : (g == 1) ? Wi : (g == 2) ? Wc : Wo;
    for (int it = 0; it < 16; ++it) {
      int e = it * 256 + tid;
      int kk = e >> 3, jj = e & 7;
      lds[g][kk][jj] = W[(size_t)(w * 512 + kk) * 1024 + n * 8 + jj];
    }
  }
  __syncthreads();
  u16* outp = wfrag + ((size_t)blockIdx.x << 14);   // 16384 elems per (n,w)
  for (int it = 0; it < 64; ++it) {
    int e = it * 256 + tid;
    int b = e & 7, lane = (e >> 3) & 63, tile = (e >> 9) & 1, ks = e >> 10;
    int kk = ks * 32 + ((lane >> 4) << 3) + b;
    int c  = tile * 16 + (lane & 15);
    int g  = c >> 3, jj = c & 7;
    outp[e] = f2bf(lds[g][kk][jj]);
  }
}

// Persistent LSTM: 128 WGs x 256 thr. WG n owns j in [8n, 8n+8) (32 gate-cols).
// Wave w holds B-frags for its K-slice [512w,512w+512) in registers (all steps).
// waves 0,1: A from h (recurrent); waves 2,3: A from x (no spin — overlaps wait).
//
// R6 protocol (R5 + h-pointer fix) — ZERO cache-maintenance ops in the hot loop:
//   h stores : relaxed agent atomic u32  (sc1 write-through -> MALL, L2 never dirty)
//   publish  : __syncthreads (vmcnt(0) drain => h MALL-acked) -> tid0 RELAXED flag
//   consume  : relaxed polls -> relaxed agent atomic u64 h loads (sc1 read-through)
//   => no buffer_wbl2, no buffer_inv; x stays L2-resident across all 512 steps.
__launch_bounds__(256, 1)
__global__ void lstm_main_kernel(
    const u16* __restrict__ xbf, const u16* __restrict__ wfrag,
    const float* __restrict__ c0,
    const float* __restrict__ bF, const float* __restrict__ bI,
    const float* __restrict__ bC, const float* __restrict__ bO,
    u16* __restrict__ hb, float* __restrict__ out, u32* flags)
{
  const int n    = blockIdx.x;
  const int tid  = threadIdx.x;
  const int w    = tid >> 6;
  const int lane = tid & 63;
  const int lr   = lane & 15;
  const int lk   = (lane >> 4) << 3;

  __shared__ float part[4][64][33];   // K-split partials, padded

  // persistent B fragments (W) — loaded once, live in registers across all steps
  bf16x8 bq[16][2];
  {
    const u16* wp = wfrag + ((size_t)(n * 4 + w) << 14) + lane * 8;
    #pragma unroll
    for (int ks = 0; ks < 16; ++ks) {
      bq[ks][0] = *reinterpret_cast<const bf16x8*>(wp + ks * 1024);
      bq[ks][1] = *reinterpret_cast<const bf16x8*>(wp + ks * 1024 + 512);
    }
  }

  // elementwise ownership: thread -> (row, jj0=even jj), c-state in fp32 registers
  const int erow = tid >> 2;
  const int ejj  = (tid & 3) << 1;
  const int j0   = n * 8 + ejj;
  float cR0 = c0[erow * 1024 + j0];
  float cR1 = c0[erow * 1024 + j0 + 1];
  const float bf0 = bF[j0], bf1 = bF[j0 + 1];
  const float bi0 = bI[j0], bi1 = bI[j0 + 1];
  const float bc0 = bC[j0], bc1 = bC[j0 + 1];
  const float bo0 = bO[j0], bo1 = bO[j0 + 1];

  #pragma unroll 1
  for (int t = 0; t < TSTEPS; ++t) {
    f32x4 acc[4][2];
    #pragma unroll
    for (int m = 0; m < 4; ++m) {
      acc[m][0] = (f32x4){0.f, 0.f, 0.f, 0.f};
      acc[m][1] = (f32x4){0.f, 0.f, 0.f, 0.f};
    }

    if (w < 2) {
      // ---- recurrent waves: wait for all WGs' step-(t-1) h (relaxed polls) ----
      if (t > 0) {
        const u32 tv = (u32)t;
        while (true) {
          u32 f0 = __hip_atomic_load(flags + lane,      __ATOMIC_RELAXED, __HIP_MEMORY_SCOPE_AGENT);
          u32 f1 = __hip_atomic_load(flags + 64 + lane, __ATOMIC_RELAXED, __HIP_MEMORY_SCOPE_AGENT);
          if (__all((f0 >= tv) && (f1 >= tv))) break;
          __builtin_amdgcn_s_sleep(1);
        }
      }
      // h loads: relaxed agent atomic u64 (sc1 read-through from MALL; no inv)
      // wave-w k-offset: 512 u16 = 1024 B = 128 u64   (R5 bug: had w*64)
      const u64* hq = (const u64*)(hb + (t & 1) * 65536) + (size_t)w * 128;
      #pragma unroll
      for (int m = 0; m < 4; ++m) {
        union { u64 q[2]; bf16x8 v; } av[16];
        #pragma unroll
        for (int ks = 0; ks < 16; ++ks) {
          int idx = (m * 16 + lr) * 256 + ks * 8 + ((lane >> 4) << 1);
          av[ks].q[0] = __hip_atomic_load(hq + idx,     __ATOMIC_RELAXED, __HIP_MEMORY_SCOPE_AGENT);
          av[ks].q[1] = __hip_atomic_load(hq + idx + 1, __ATOMIC_RELAXED, __HIP_MEMORY_SCOPE_AGENT);
        }
        #pragma unroll
        for (int ks = 0; ks < 16; ++ks) {
          acc[m][0] = __builtin_amdgcn_mfma_f32_16x16x32_bf16(av[ks].v, bq[ks][0], acc[m][0], 0, 0, 0);
          acc[m][1] = __builtin_amdgcn_mfma_f32_16x16x32_bf16(av[ks].v, bq[ks][1], acc[m][1], 0, 0, 0);
        }
      }
    } else {
      // ---- x waves: independent of h_t — plain cached loads, L2-resident ----
      const u16* asrc = xbf + (size_t)t * 65536 + (w - 2) * 512;
      #pragma unroll
      for (int ks = 0; ks < 16; ++ks) {
        #pragma unroll
        for (int m = 0; m < 4; ++m) {
          bf16x8 av = *reinterpret_cast<const bf16x8*>(asrc + (m * 16 + lr) * 1024 + ks * 32 + lk);
          acc[m][0] = __builtin_amdgcn_mfma_f32_16x16x32_bf16(av, bq[ks][0], acc[m][0], 0, 0, 0);
          acc[m][1] = __builtin_amdgcn_mfma_f32_16x16x32_bf16(av, bq[ks][1], acc[m][1], 0, 0, 0);
        }
      }
    }

    // write K-split partials: D row = m*16 + (lane>>4)*4 + r, col = nt*16 + lr
    #pragma unroll
    for (int m = 0; m < 4; ++m)
      #pragma unroll
      for (int nt = 0; nt < 2; ++nt)
        #pragma unroll
        for (int r = 0; r < 4; ++r)
          part[w][m * 16 + ((lane >> 4) << 2) + r][nt * 16 + lr] = acc[m][nt][r];

    __syncthreads();

    // reduce 4 partials + bias + gates + state update (2 elems per thread)
    float a8[8];
    #pragma unroll
    for (int q = 0; q < 2; ++q) {
      int jj = ejj + q;
      #pragma unroll
      for (int g = 0; g < 4; ++g)
        a8[q * 4 + g] = part[0][erow][g * 8 + jj] + part[1][erow][g * 8 + jj]
                      + part[2][erow][g * 8 + jj] + part[3][erow][g * 8 + jj];
    }
    float fA = sigf(a8[0] + bf0), iA = sigf(a8[1] + bi0);
    float gA = tanhfast(a8[2] + bc0), oA = sigf(a8[3] + bo0);
    float cn0 = fA * cR0 + iA * gA;
    float hn0 = oA * tanhfast(cn0);
    cR0 = cn0;
    float fB = sigf(a8[4] + bf1), iB = sigf(a8[5] + bi1);
    float gB = tanhfast(a8[6] + bc1), oB = sigf(a8[7] + bo1);
    float cn1 = fB * cR1 + iB * gB;
    float hn1 = oB * tanhfast(cn1);
    cR1 = cn1;

    // h exchange: relaxed agent atomic u32 store (sc1 write-through to MALL)
    {
      u32 hv = (u32)f2bf(hn0) | ((u32)f2bf(hn1) << 16);
      u32* hdst32 = (u32*)(hb + ((t + 1) & 1) * 65536) + erow * 512 + (j0 >> 1);
      __hip_atomic_store(hdst32, hv, __ATOMIC_RELAXED, __HIP_MEMORY_SCOPE_AGENT);
    }
    // fp32 outputs (plain cached stores; nobody re-reads them)
    size_t ob = (size_t)t * 65536 + erow * 1024 + j0;
    out[ob]     = hn0;
    out[ob + 1] = hn1;
    if (t == TSTEPS - 1) {
      out[33554432 + erow * 1024 + j0]     = hn0;   // h_last
      out[33554432 + erow * 1024 + j0 + 1] = hn1;
      out[33619968 + erow * 1024 + j0]     = cn0;   // c_last
      out[33619968 + erow * 1024 + j0 + 1] = cn1;
    }

    // publish: __syncthreads waits vmcnt(0) per wave before s_barrier, so every
    // thread's sc1 h-store is MALL-acked before tid0's flag store issues.
    // Flag store is RELAXED -> no wbl2; it is ordered by completion, not fence.
    __syncthreads();
    if (t < TSTEPS - 1 && tid == 0)
      __hip_atomic_store(flags + n, (u32)(t + 1), __ATOMIC_RELAXED, __HIP_MEMORY_SCOPE_AGENT);
  }
}

extern "C" void kernel_launch(void* const* d_in, const int* in_sizes, int n_in,
                              void* d_out, int out_size, void* d_ws, size_t ws_size,
                              hipStream_t stream) {
  const float* x  = (const float*)d_in[0];
  const float* h0 = (const float*)d_in[1];
  const float* c0 = (const float*)d_in[2];
  const float* Wf = (const float*)d_in[3];
  const float* bf = (const float*)d_in[4];
  const float* Wi = (const float*)d_in[5];
  const float* bi = (const float*)d_in[6];
  const float* Wc = (const float*)d_in[7];
  const float* bc = (const float*)d_in[8];
  const float* Wo = (const float*)d_in[9];
  const float* bo = (const float*)d_in[10];

  // workspace layout: wfrag 16MB | xbf 64MB | hb 256KB | flags 512B
  if (ws_size < ((80u << 20) + (1u << 18) + 1024)) return;
  char* ws   = (char*)d_ws;
  u16* wfrag = (u16*)ws;
  u16* xbf   = (u16*)(ws + (16u << 20));
  u16* hb    = (u16*)(ws + (80u << 20));
  u32* flags = (u32*)(ws + (80u << 20) + (1u << 18));
  float* outp = (float*)d_out;

  hipMemsetAsync(flags, 0, 512, stream);
  convert_x_kernel<<<2048, 256, 0, stream>>>(x, xbf, (long)512 * 64 * 1024);
  convert_x_kernel<<<64, 256, 0, stream>>>(h0, hb, 65536);
  arrange_w_kernel<<<512, 256, 0, stream>>>(Wf, Wi, Wc, Wo, wfrag);

  void* args[] = {(void*)&xbf, (void*)&wfrag, (void*)&c0, (void*)&bf, (void*)&bi,
                  (void*)&bc, (void*)&bo, (void*)&hb, (void*)&outp, (void*)&flags};
  hipError_t e = hipLaunchCooperativeKernel((const void*)lstm_main_kernel, dim3(NWG),
                                            dim3(256), args, 0, stream);
  if (e != hipSuccess) {
    // 128 WGs at 1 WG/CU on 256 CUs are trivially co-resident; plain launch is
    // a safe fallback so a silent cooperative-launch failure can't stub the run.
    lstm_main_kernel<<<dim3(NWG), dim3(256), 0, stream>>>(xbf, wfrag, c0, bf, bi,
                                                          bc, bo, hb, outp, flags);
  }
}

// Round 7
// 5837.685 us; speedup vs baseline: 1.9245x; 1.2755x over previous
//
#include <hip/hip_runtime.h>

typedef unsigned short u16;
typedef unsigned int   u32;
typedef unsigned long long u64;
typedef __attribute__((ext_vector_type(8))) __bf16 bf16x8;
typedef __attribute__((ext_vector_type(4))) float  f32x4;

#define NWG    128
#define TSTEPS 512

// ---------------- helpers ----------------
__device__ __forceinline__ u16 f2bf(float f) {
  union { float f; u32 u; } v; v.f = f;
  return (u16)((v.u + 0x7FFFu + ((v.u >> 16) & 1u)) >> 16);  // RNE
}
__device__ __forceinline__ float sigf(float x)     { return 1.f / (1.f + __expf(-x)); }
__device__ __forceinline__ float tanhfast(float x) { return 2.f / (1.f + __expf(-2.f * x)) - 1.f; }

// fp32 -> bf16 bulk convert (x only; h0 uses the tiled converter below)
__global__ void convert_x_kernel(const float* __restrict__ x, u16* __restrict__ xb, long n) {
  long i = (long)(blockIdx.x * blockDim.x + threadIdx.x) * 4;
  long stride = (long)gridDim.x * blockDim.x * 4;
  for (; i < n; i += stride) {
    float4 v = *reinterpret_cast<const float4*>(x + i);
    ushort4 o; o.x = f2bf(v.x); o.y = f2bf(v.y); o.z = f2bf(v.z); o.w = f2bf(v.w);
    *reinterpret_cast<ushort4*>(xb + i) = o;
  }
}

// h tiled layout (1KB tiles, matches the MFMA A-fragment gather exactly):
//   tile_m = row>>4, tile_k = k>>5, elem = (tile_m*32 + tile_k)*512
//                                        + (row&15)*32 + ((k>>3)&3)*8 + (k&7)
__global__ void convert_h0_tiled(const float* __restrict__ h0, u16* __restrict__ hb) {
  int gid = blockIdx.x * blockDim.x + threadIdx.x;   // 32768 u32 units (2 elems each)
  int row = gid >> 9;
  int k0  = (gid & 511) << 1;
  float a = h0[row * 1024 + k0];
  float b = h0[row * 1024 + k0 + 1];
  int off = ((row >> 4) * 32 + (k0 >> 5)) * 512 + (row & 15) * 32 + ((k0 >> 3) & 3) * 8 + (k0 & 7);
  u32 hv = (u32)f2bf(a) | ((u32)f2bf(b) << 16);
  *((u32*)hb + (off >> 1)) = hv;
}

// Gather W into exact per-(wg,wave,ks,tile,lane) MFMA B-fragment order, bf16.
// (identical to the R1/R4/R6 PASSING version)
__global__ void arrange_w_kernel(const float* __restrict__ Wf, const float* __restrict__ Wi,
                                 const float* __restrict__ Wc, const float* __restrict__ Wo,
                                 u16* __restrict__ wfrag) {
  __shared__ float lds[4][512][8];
  const int n = blockIdx.x >> 2;      // 0..127
  const int w = blockIdx.x & 3;       // 0..3
  const int tid = threadIdx.x;
  #pragma unroll
  for (int g = 0; g < 4; ++g) {
    const float* W = (g == 0) ? Wf : (g == 1) ? Wi : (g == 2) ? Wc : Wo;
    for (int it = 0; it < 16; ++it) {
      int e = it * 256 + tid;
      int kk = e >> 3, jj = e & 7;
      lds[g][kk][jj] = W[(size_t)(w * 512 + kk) * 1024 + n * 8 + jj];
    }
  }
  __syncthreads();
  u16* outp = wfrag + ((size_t)blockIdx.x << 14);   // 16384 elems per (n,w)
  for (int it = 0; it < 64; ++it) {
    int e = it * 256 + tid;
    int b = e & 7, lane = (e >> 3) & 63, tile = (e >> 9) & 1, ks = e >> 10;
    int kk = ks * 32 + ((lane >> 4) << 3) + b;
    int c  = tile * 16 + (lane & 15);
    int g  = c >> 3, jj = c & 7;
    outp[e] = f2bf(lds[g][kk][jj]);
  }
}

// Persistent LSTM: 128 WGs x 256 thr. WG n owns j in [8n, 8n+8) (32 gate-cols).
// R7 = R6 protocol (zero cache maintenance, relaxed sc1 write/read-through)
// + TILED h buffer so the h gather is fully coalesced (1KB per instruction-pair)
// + part stride 36 (write conflicts 4-way -> free 2-way).
__launch_bounds__(256, 1)
__global__ void lstm_main_kernel(
    const u16* __restrict__ xbf, const u16* __restrict__ wfrag,
    const float* __restrict__ c0,
    const float* __restrict__ bF, const float* __restrict__ bI,
    const float* __restrict__ bC, const float* __restrict__ bO,
    u16* __restrict__ hb, float* __restrict__ out, u32* flags)
{
  const int n    = blockIdx.x;
  const int tid  = threadIdx.x;
  const int w    = tid >> 6;
  const int lane = tid & 63;
  const int lr   = lane & 15;
  const int hi   = lane >> 4;
  const int lk   = hi << 3;

  __shared__ float part[4][64][36];   // K-split partials, stride 36 (2-way-free banks)

  // persistent B fragments (W) — loaded once, live in registers across all steps
  bf16x8 bq[16][2];
  {
    const u16* wp = wfrag + ((size_t)(n * 4 + w) << 14) + lane * 8;
    #pragma unroll
    for (int ks = 0; ks < 16; ++ks) {
      bq[ks][0] = *reinterpret_cast<const bf16x8*>(wp + ks * 1024);
      bq[ks][1] = *reinterpret_cast<const bf16x8*>(wp + ks * 1024 + 512);
    }
  }

  // elementwise ownership: thread -> (row, jj0=even jj), c-state in fp32 registers
  const int erow = tid >> 2;
  const int ejj  = (tid & 3) << 1;
  const int j0   = n * 8 + ejj;
  float cR0 = c0[erow * 1024 + j0];
  float cR1 = c0[erow * 1024 + j0 + 1];
  const float bf0 = bF[j0], bf1 = bF[j0 + 1];
  const float bi0 = bI[j0], bi1 = bI[j0 + 1];
  const float bc0 = bC[j0], bc1 = bC[j0 + 1];
  const float bo0 = bO[j0], bo1 = bO[j0 + 1];
  // tiled h-store offset (constant per thread): row=erow, k=j0 (j0 even)
  const int hoff_u32 = (((erow >> 4) * 32 + (j0 >> 5)) * 512
                        + (erow & 15) * 32 + ((j0 >> 3) & 3) * 8 + (j0 & 7)) >> 1;

  #pragma unroll 1
  for (int t = 0; t < TSTEPS; ++t) {
    f32x4 acc[4][2];
    #pragma unroll
    for (int m = 0; m < 4; ++m) {
      acc[m][0] = (f32x4){0.f, 0.f, 0.f, 0.f};
      acc[m][1] = (f32x4){0.f, 0.f, 0.f, 0.f};
    }

    if (w < 2) {
      // ---- recurrent waves: wait for all WGs' step-(t-1) h (relaxed polls) ----
      if (t > 0) {
        const u32 tv = (u32)t;
        while (true) {
          u32 f0 = __hip_atomic_load(flags + lane,      __ATOMIC_RELAXED, __HIP_MEMORY_SCOPE_AGENT);
          u32 f1 = __hip_atomic_load(flags + 64 + lane, __ATOMIC_RELAXED, __HIP_MEMORY_SCOPE_AGENT);
          if (__all((f0 >= tv) && (f1 >= tv))) break;
          __builtin_amdgcn_s_sleep(1);
        }
      }
      // h loads from TILED buffer: lane (lr,hi) reads u64s at tile*128 + lr*8 + hi*2
      // -> one instruction-pair covers one contiguous 1KB tile (fully coalesced).
      const u64* hq = (const u64*)(hb + (t & 1) * 65536);
      #pragma unroll
      for (int m = 0; m < 4; ++m) {
        union { u64 q[2]; bf16x8 v; } av[16];
        #pragma unroll
        for (int ks = 0; ks < 16; ++ks) {
          int idx = (m * 32 + w * 16 + ks) * 128 + lr * 8 + hi * 2;
          av[ks].q[0] = __hip_atomic_load(hq + idx,     __ATOMIC_RELAXED, __HIP_MEMORY_SCOPE_AGENT);
          av[ks].q[1] = __hip_atomic_load(hq + idx + 1, __ATOMIC_RELAXED, __HIP_MEMORY_SCOPE_AGENT);
        }
        #pragma unroll
        for (int ks = 0; ks < 16; ++ks) {
          acc[m][0] = __builtin_amdgcn_mfma_f32_16x16x32_bf16(av[ks].v, bq[ks][0], acc[m][0], 0, 0, 0);
          acc[m][1] = __builtin_amdgcn_mfma_f32_16x16x32_bf16(av[ks].v, bq[ks][1], acc[m][1], 0, 0, 0);
        }
      }
    } else {
      // ---- x waves: independent of h_t — plain cached loads, L2-resident ----
      const u16* asrc = xbf + (size_t)t * 65536 + (w - 2) * 512;
      #pragma unroll
      for (int ks = 0; ks < 16; ++ks) {
        #pragma unroll
        for (int m = 0; m < 4; ++m) {
          bf16x8 av = *reinterpret_cast<const bf16x8*>(asrc + (m * 16 + lr) * 1024 + ks * 32 + lk);
          acc[m][0] = __builtin_amdgcn_mfma_f32_16x16x32_bf16(av, bq[ks][0], acc[m][0], 0, 0, 0);
          acc[m][1] = __builtin_amdgcn_mfma_f32_16x16x32_bf16(av, bq[ks][1], acc[m][1], 0, 0, 0);
        }
      }
    }

    // write K-split partials: D row = m*16 + hi*4 + r, col = nt*16 + lr
    #pragma unroll
    for (int m = 0; m < 4; ++m)
      #pragma unroll
      for (int nt = 0; nt < 2; ++nt)
        #pragma unroll
        for (int r = 0; r < 4; ++r)
          part[w][m * 16 + (hi << 2) + r][nt * 16 + lr] = acc[m][nt][r];

    __syncthreads();

    // reduce 4 partials + bias + gates + state update (2 elems per thread)
    float a8[8];
    #pragma unroll
    for (int q = 0; q < 2; ++q) {
      int jj = ejj + q;
      #pragma unroll
      for (int g = 0; g < 4; ++g)
        a8[q * 4 + g] = part[0][erow][g * 8 + jj] + part[1][erow][g * 8 + jj]
                      + part[2][erow][g * 8 + jj] + part[3][erow][g * 8 + jj];
    }
    float fA = sigf(a8[0] + bf0), iA = sigf(a8[1] + bi0);
    float gA = tanhfast(a8[2] + bc0), oA = sigf(a8[3] + bo0);
    float cn0 = fA * cR0 + iA * gA;
    float hn0 = oA * tanhfast(cn0);
    cR0 = cn0;
    float fB = sigf(a8[4] + bf1), iB = sigf(a8[5] + bi1);
    float gB = tanhfast(a8[6] + bc1), oB = sigf(a8[7] + bo1);
    float cn1 = fB * cR1 + iB * gB;
    float hn1 = oB * tanhfast(cn1);
    cR1 = cn1;

    // h exchange: relaxed agent atomic u32 store into the TILED buffer
    {
      u32 hv = (u32)f2bf(hn0) | ((u32)f2bf(hn1) << 16);
      u32* hdst32 = (u32*)(hb + ((t + 1) & 1) * 65536) + hoff_u32;
      __hip_atomic_store(hdst32, hv, __ATOMIC_RELAXED, __HIP_MEMORY_SCOPE_AGENT);
    }
    // fp32 outputs (plain cached stores; nobody re-reads them)
    size_t ob = (size_t)t * 65536 + erow * 1024 + j0;
    out[ob]     = hn0;
    out[ob + 1] = hn1;
    if (t == TSTEPS - 1) {
      out[33554432 + erow * 1024 + j0]     = hn0;   // h_last
      out[33554432 + erow * 1024 + j0 + 1] = hn1;
      out[33619968 + erow * 1024 + j0]     = cn0;   // c_last
      out[33619968 + erow * 1024 + j0 + 1] = cn1;
    }

    // publish: __syncthreads waits vmcnt(0) per wave before s_barrier, so every
    // thread's sc1 h-store is MALL-acked before tid0's flag store issues.
    __syncthreads();
    if (t < TSTEPS - 1 && tid == 0)
      __hip_atomic_store(flags + n, (u32)(t + 1), __ATOMIC_RELAXED, __HIP_MEMORY_SCOPE_AGENT);
  }
}

extern "C" void kernel_launch(void* const* d_in, const int* in_sizes, int n_in,
                              void* d_out, int out_size, void* d_ws, size_t ws_size,
                              hipStream_t stream) {
  const float* x  = (const float*)d_in[0];
  const float* h0 = (const float*)d_in[1];
  const float* c0 = (const float*)d_in[2];
  const float* Wf = (const float*)d_in[3];
  const float* bf = (const float*)d_in[4];
  const float* Wi = (const float*)d_in[5];
  const float* bi = (const float*)d_in[6];
  const float* Wc = (const float*)d_in[7];
  const float* bc = (const float*)d_in[8];
  const float* Wo = (const float*)d_in[9];
  const float* bo = (const float*)d_in[10];

  // workspace layout: wfrag 16MB | xbf 64MB | hb 256KB | flags 512B
  if (ws_size < ((80u << 20) + (1u << 18) + 1024)) return;
  char* ws   = (char*)d_ws;
  u16* wfrag = (u16*)ws;
  u16* xbf   = (u16*)(ws + (16u << 20));
  u16* hb    = (u16*)(ws + (80u << 20));
  u32* flags = (u32*)(ws + (80u << 20) + (1u << 18));
  float* outp = (float*)d_out;

  hipMemsetAsync(flags, 0, 512, stream);
  convert_x_kernel<<<2048, 256, 0, stream>>>(x, xbf, (long)512 * 64 * 1024);
  convert_h0_tiled<<<128, 256, 0, stream>>>(h0, hb);
  arrange_w_kernel<<<512, 256, 0, stream>>>(Wf, Wi, Wc, Wo, wfrag);

  void* args[] = {(void*)&xbf, (void*)&wfrag, (void*)&c0, (void*)&bf, (void*)&bi,
                  (void*)&bc, (void*)&bo, (void*)&hb, (void*)&outp, (void*)&flags};
  hipError_t e = hipLaunchCooperativeKernel((const void*)lstm_main_kernel, dim3(NWG),
                                            dim3(256), args, 0, stream);
  if (e != hipSuccess) {
    // 128 WGs at 1 WG/CU on 256 CUs are trivially co-resident; plain launch is
    // a safe fallback so a silent cooperative-launch failure can't stub the run.
    lstm_main_kernel<<<dim3(NWG), dim3(256), 0, stream>>>(xbf, wfrag, c0, bf, bi,
                                                          bc, bo, hb, outp, flags);
  }
}

// Round 8
// 5316.178 us; speedup vs baseline: 2.1133x; 1.0981x over previous
//
#include <hip/hip_runtime.h>

typedef unsigned short u16;
typedef unsigned int   u32;
typedef unsigned long long u64;
typedef __attribute__((ext_vector_type(8))) __bf16 bf16x8;
typedef __attribute__((ext_vector_type(4))) float  f32x4;

#define NWG    128
#define TSTEPS 512

// ---------------- helpers ----------------
__device__ __forceinline__ u16 f2bf(float f) {
  union { float f; u32 u; } v; v.f = f;
  return (u16)((v.u + 0x7FFFu + ((v.u >> 16) & 1u)) >> 16);  // RNE
}
__device__ __forceinline__ float sigf(float x)     { return 1.f / (1.f + __expf(-x)); }
__device__ __forceinline__ float tanhfast(float x) { return 2.f / (1.f + __expf(-2.f * x)) - 1.f; }

// fp32 -> bf16 bulk convert (x only; h0 uses the tiled converter below)
__global__ void convert_x_kernel(const float* __restrict__ x, u16* __restrict__ xb, long n) {
  long i = (long)(blockIdx.x * blockDim.x + threadIdx.x) * 4;
  long stride = (long)gridDim.x * blockDim.x * 4;
  for (; i < n; i += stride) {
    float4 v = *reinterpret_cast<const float4*>(x + i);
    ushort4 o; o.x = f2bf(v.x); o.y = f2bf(v.y); o.z = f2bf(v.z); o.w = f2bf(v.w);
    *reinterpret_cast<ushort4*>(xb + i) = o;
  }
}

// h tiled layout (1KB tiles, matches the MFMA A-fragment gather exactly):
//   tile_m = row>>4, tile_k = k>>5, elem = (tile_m*32 + tile_k)*512
//                                        + (row&15)*32 + ((k>>3)&3)*8 + (k&7)
__global__ void convert_h0_tiled(const float* __restrict__ h0, u16* __restrict__ hb) {
  int gid = blockIdx.x * blockDim.x + threadIdx.x;   // 32768 u32 units (2 elems each)
  int row = gid >> 9;
  int k0  = (gid & 511) << 1;
  float a = h0[row * 1024 + k0];
  float b = h0[row * 1024 + k0 + 1];
  int off = ((row >> 4) * 32 + (k0 >> 5)) * 512 + (row & 15) * 32 + ((k0 >> 3) & 3) * 8 + (k0 & 7);
  u32 hv = (u32)f2bf(a) | ((u32)f2bf(b) << 16);
  *((u32*)hb + (off >> 1)) = hv;
}

// Gather W into exact per-(wg,wave,ks,tile,lane) MFMA B-fragment order, bf16.
// (identical to the R1/R4/R6/R7 PASSING version)
__global__ void arrange_w_kernel(const float* __restrict__ Wf, const float* __restrict__ Wi,
                                 const float* __restrict__ Wc, const float* __restrict__ Wo,
                                 u16* __restrict__ wfrag) {
  __shared__ float lds[4][512][8];
  const int n = blockIdx.x >> 2;      // 0..127
  const int w = blockIdx.x & 3;       // 0..3
  const int tid = threadIdx.x;
  #pragma unroll
  for (int g = 0; g < 4; ++g) {
    const float* W = (g == 0) ? Wf : (g == 1) ? Wi : (g == 2) ? Wc : Wo;
    for (int it = 0; it < 16; ++it) {
      int e = it * 256 + tid;
      int kk = e >> 3, jj = e & 7;
      lds[g][kk][jj] = W[(size_t)(w * 512 + kk) * 1024 + n * 8 + jj];
    }
  }
  __syncthreads();
  u16* outp = wfrag + ((size_t)blockIdx.x << 14);   // 16384 elems per (n,w)
  for (int it = 0; it < 64; ++it) {
    int e = it * 256 + tid;
    int b = e & 7, lane = (e >> 3) & 63, tile = (e >> 9) & 1, ks = e >> 10;
    int kk = ks * 32 + ((lane >> 4) << 3) + b;
    int c  = tile * 16 + (lane & 15);
    int g  = c >> 3, jj = c & 7;
    outp[e] = f2bf(lds[g][kk][jj]);
  }
}

// Persistent LSTM: 128 worker WGs + 1 aggregator WG, 256 thr each.
// R8 = R7 data path (tiled h, zero cache maintenance) + LOW-CONTENTION SYNC:
//   producers : tid0 relaxed flag[n]=t+1 after vmcnt-draining barrier (as R7)
//   aggregator: WG 128 (sole reader of flags) -> single relaxed epoch=t store
//   consumers : wave 0 polls epoch (one u32, one request/wave), signals wave 1
//               via LDS; waves 2,3 never spin.
__launch_bounds__(256, 1)
__global__ void lstm_main_kernel(
    const u16* __restrict__ xbf, const u16* __restrict__ wfrag,
    const float* __restrict__ c0,
    const float* __restrict__ bF, const float* __restrict__ bI,
    const float* __restrict__ bC, const float* __restrict__ bO,
    u16* __restrict__ hb, float* __restrict__ out, u32* flags)
{
  const int n    = blockIdx.x;
  const int tid  = threadIdx.x;
  u32* const epoch = flags + 192;     // own 64B line, away from flags[0..127]

  // ---------------- aggregator WG: turn 128 flags into one epoch word --------
  if (n == NWG) {
    if (tid < 64) {
      for (u32 tv = 1; tv < TSTEPS; ++tv) {
        while (true) {
          u32 f0 = __hip_atomic_load(flags + tid,      __ATOMIC_RELAXED, __HIP_MEMORY_SCOPE_AGENT);
          u32 f1 = __hip_atomic_load(flags + 64 + tid, __ATOMIC_RELAXED, __HIP_MEMORY_SCOPE_AGENT);
          if (__all((f0 >= tv) && (f1 >= tv))) break;
          __builtin_amdgcn_s_sleep(1);
        }
        if (tid == 0)
          __hip_atomic_store(epoch, tv, __ATOMIC_RELAXED, __HIP_MEMORY_SCOPE_AGENT);
      }
    }
    return;
  }

  const int w    = tid >> 6;
  const int lane = tid & 63;
  const int lr   = lane & 15;
  const int hi   = lane >> 4;
  const int lk   = hi << 3;

  __shared__ float part[4][64][36];   // K-split partials, stride 36 (2-way-free banks)
  __shared__ u32 go;                  // wave0 -> wave1 step signal (LDS only)

  // persistent B fragments (W) — loaded once, live in registers across all steps
  bf16x8 bq[16][2];
  {
    const u16* wp = wfrag + ((size_t)(n * 4 + w) << 14) + lane * 8;
    #pragma unroll
    for (int ks = 0; ks < 16; ++ks) {
      bq[ks][0] = *reinterpret_cast<const bf16x8*>(wp + ks * 1024);
      bq[ks][1] = *reinterpret_cast<const bf16x8*>(wp + ks * 1024 + 512);
    }
  }
  if (tid == 0) go = 0;
  __syncthreads();

  // elementwise ownership: thread -> (row, jj0=even jj), c-state in fp32 registers
  const int erow = tid >> 2;
  const int ejj  = (tid & 3) << 1;
  const int j0   = n * 8 + ejj;
  float cR0 = c0[erow * 1024 + j0];
  float cR1 = c0[erow * 1024 + j0 + 1];
  const float bf0 = bF[j0], bf1 = bF[j0 + 1];
  const float bi0 = bI[j0], bi1 = bI[j0 + 1];
  const float bc0 = bC[j0], bc1 = bC[j0 + 1];
  const float bo0 = bO[j0], bo1 = bO[j0 + 1];
  // tiled h-store offset (constant per thread): row=erow, k=j0 (j0 even)
  const int hoff_u32 = (((erow >> 4) * 32 + (j0 >> 5)) * 512
                        + (erow & 15) * 32 + ((j0 >> 3) & 3) * 8 + (j0 & 7)) >> 1;

  #pragma unroll 1
  for (int t = 0; t < TSTEPS; ++t) {
    f32x4 acc[4][2];
    #pragma unroll
    for (int m = 0; m < 4; ++m) {
      acc[m][0] = (f32x4){0.f, 0.f, 0.f, 0.f};
      acc[m][1] = (f32x4){0.f, 0.f, 0.f, 0.f};
    }

    if (w < 2) {
      // ---- wait for step-(t-1) h: wave0 polls epoch; wave1 waits on LDS ----
      if (t > 0) {
        const u32 tv = (u32)t;
        if (w == 0) {
          while (__hip_atomic_load(epoch, __ATOMIC_RELAXED, __HIP_MEMORY_SCOPE_AGENT) < tv)
            __builtin_amdgcn_s_sleep(4);
          if (lane == 0)
            __hip_atomic_store(&go, tv, __ATOMIC_RELAXED, __HIP_MEMORY_SCOPE_WORKGROUP);
        } else {
          while (__hip_atomic_load(&go, __ATOMIC_RELAXED, __HIP_MEMORY_SCOPE_WORKGROUP) < tv)
            __builtin_amdgcn_s_sleep(1);
        }
      }
      // h loads from TILED buffer: lane (lr,hi) reads u64s at tile*128 + lr*8 + hi*2
      const u64* hq = (const u64*)(hb + (t & 1) * 65536);
      #pragma unroll
      for (int m = 0; m < 4; ++m) {
        union { u64 q[2]; bf16x8 v; } av[16];
        #pragma unroll
        for (int ks = 0; ks < 16; ++ks) {
          int idx = (m * 32 + w * 16 + ks) * 128 + lr * 8 + hi * 2;
          av[ks].q[0] = __hip_atomic_load(hq + idx,     __ATOMIC_RELAXED, __HIP_MEMORY_SCOPE_AGENT);
          av[ks].q[1] = __hip_atomic_load(hq + idx + 1, __ATOMIC_RELAXED, __HIP_MEMORY_SCOPE_AGENT);
        }
        #pragma unroll
        for (int ks = 0; ks < 16; ++ks) {
          acc[m][0] = __builtin_amdgcn_mfma_f32_16x16x32_bf16(av[ks].v, bq[ks][0], acc[m][0], 0, 0, 0);
          acc[m][1] = __builtin_amdgcn_mfma_f32_16x16x32_bf16(av[ks].v, bq[ks][1], acc[m][1], 0, 0, 0);
        }
      }
    } else {
      // ---- x waves: independent of h_t — plain cached loads ----
      const u16* asrc = xbf + (size_t)t * 65536 + (w - 2) * 512;
      #pragma unroll
      for (int ks = 0; ks < 16; ++ks) {
        #pragma unroll
        for (int m = 0; m < 4; ++m) {
          bf16x8 av = *reinterpret_cast<const bf16x8*>(asrc + (m * 16 + lr) * 1024 + ks * 32 + lk);
          acc[m][0] = __builtin_amdgcn_mfma_f32_16x16x32_bf16(av, bq[ks][0], acc[m][0], 0, 0, 0);
          acc[m][1] = __builtin_amdgcn_mfma_f32_16x16x32_bf16(av, bq[ks][1], acc[m][1], 0, 0, 0);
        }
      }
    }

    // write K-split partials: D row = m*16 + hi*4 + r, col = nt*16 + lr
    #pragma unroll
    for (int m = 0; m < 4; ++m)
      #pragma unroll
      for (int nt = 0; nt < 2; ++nt)
        #pragma unroll
        for (int r = 0; r < 4; ++r)
          part[w][m * 16 + (hi << 2) + r][nt * 16 + lr] = acc[m][nt][r];

    __syncthreads();

    // reduce 4 partials + bias + gates + state update (2 elems per thread)
    float a8[8];
    #pragma unroll
    for (int q = 0; q < 2; ++q) {
      int jj = ejj + q;
      #pragma unroll
      for (int g = 0; g < 4; ++g)
        a8[q * 4 + g] = part[0][erow][g * 8 + jj] + part[1][erow][g * 8 + jj]
                      + part[2][erow][g * 8 + jj] + part[3][erow][g * 8 + jj];
    }
    float fA = sigf(a8[0] + bf0), iA = sigf(a8[1] + bi0);
    float gA = tanhfast(a8[2] + bc0), oA = sigf(a8[3] + bo0);
    float cn0 = fA * cR0 + iA * gA;
    float hn0 = oA * tanhfast(cn0);
    cR0 = cn0;
    float fB = sigf(a8[4] + bf1), iB = sigf(a8[5] + bi1);
    float gB = tanhfast(a8[6] + bc1), oB = sigf(a8[7] + bo1);
    float cn1 = fB * cR1 + iB * gB;
    float hn1 = oB * tanhfast(cn1);
    cR1 = cn1;

    // h exchange: relaxed agent atomic u32 store into the TILED buffer
    {
      u32 hv = (u32)f2bf(hn0) | ((u32)f2bf(hn1) << 16);
      u32* hdst32 = (u32*)(hb + ((t + 1) & 1) * 65536) + hoff_u32;
      __hip_atomic_store(hdst32, hv, __ATOMIC_RELAXED, __HIP_MEMORY_SCOPE_AGENT);
    }
    // fp32 outputs (plain cached stores; nobody re-reads them)
    size_t ob = (size_t)t * 65536 + erow * 1024 + j0;
    out[ob]     = hn0;
    out[ob + 1] = hn1;
    if (t == TSTEPS - 1) {
      out[33554432 + erow * 1024 + j0]     = hn0;   // h_last
      out[33554432 + erow * 1024 + j0 + 1] = hn1;
      out[33619968 + erow * 1024 + j0]     = cn0;   // c_last
      out[33619968 + erow * 1024 + j0 + 1] = cn1;
    }

    // publish: __syncthreads waits vmcnt(0) per wave before s_barrier, so every
    // thread's sc1 h-store is MALL-acked before tid0's flag store issues.
    __syncthreads();
    if (t < TSTEPS - 1 && tid == 0)
      __hip_atomic_store(flags + n, (u32)(t + 1), __ATOMIC_RELAXED, __HIP_MEMORY_SCOPE_AGENT);
  }
}

extern "C" void kernel_launch(void* const* d_in, const int* in_sizes, int n_in,
                              void* d_out, int out_size, void* d_ws, size_t ws_size,
                              hipStream_t stream) {
  const float* x  = (const float*)d_in[0];
  const float* h0 = (const float*)d_in[1];
  const float* c0 = (const float*)d_in[2];
  const float* Wf = (const float*)d_in[3];
  const float* bf = (const float*)d_in[4];
  const float* Wi = (const float*)d_in[5];
  const float* bi = (const float*)d_in[6];
  const float* Wc = (const float*)d_in[7];
  const float* bc = (const float*)d_in[8];
  const float* Wo = (const float*)d_in[9];
  const float* bo = (const float*)d_in[10];

  // workspace layout: wfrag 16MB | xbf 64MB | hb 256KB | flags/epoch 1KB
  if (ws_size < ((80u << 20) + (1u << 18) + 1024)) return;
  char* ws   = (char*)d_ws;
  u16* wfrag = (u16*)ws;
  u16* xbf   = (u16*)(ws + (16u << 20));
  u16* hb    = (u16*)(ws + (80u << 20));
  u32* flags = (u32*)(ws + (80u << 20) + (1u << 18));
  float* outp = (float*)d_out;

  hipMemsetAsync(flags, 0, 1024, stream);
  convert_x_kernel<<<2048, 256, 0, stream>>>(x, xbf, (long)512 * 64 * 1024);
  convert_h0_tiled<<<128, 256, 0, stream>>>(h0, hb);
  arrange_w_kernel<<<512, 256, 0, stream>>>(Wf, Wi, Wc, Wo, wfrag);

  void* args[] = {(void*)&xbf, (void*)&wfrag, (void*)&c0, (void*)&bf, (void*)&bi,
                  (void*)&bc, (void*)&bo, (void*)&hb, (void*)&outp, (void*)&flags};
  hipError_t e = hipLaunchCooperativeKernel((const void*)lstm_main_kernel, dim3(NWG + 1),
                                            dim3(256), args, 0, stream);
  if (e != hipSuccess) {
    // 129 WGs at 1 WG/CU on 256 CUs are trivially co-resident; plain launch is
    // a safe fallback so a silent cooperative-launch failure can't stub the run.
    lstm_main_kernel<<<dim3(NWG + 1), dim3(256), 0, stream>>>(xbf, wfrag, c0, bf, bi,
                                                              bc, bo, hb, outp, flags);
  }
}